// Round 4
// baseline (112.196 us; speedup 1.0000x reference)
//
#include <hip/hip_runtime.h>
#include <math.h>

#define NN 512

typedef __attribute__((ext_vector_type(8))) short bf16x8;
typedef __attribute__((ext_vector_type(4))) float f32x4;
typedef __attribute__((ext_vector_type(4))) unsigned int u32x4;

__device__ inline unsigned short f2bf(float f) {
    unsigned u = __builtin_bit_cast(unsigned, f);
    u += 0x7fffu + ((u >> 16) & 1u);   // round-to-nearest-even
    return (unsigned short)(u >> 16);
}
__device__ inline float bf2f(unsigned short h) {
    unsigned u = ((unsigned)h) << 16;
    return __builtin_bit_cast(float, u);
}
__device__ inline unsigned cvtpk_bf16(float lo, float hi) {
    unsigned r;
    asm("v_cvt_pk_bf16_f32 %0, %1, %2" : "=v"(r) : "v"(lo), "v"(hi));
    return r;
}

// Parity-split DCT matrices: Ce[kk][n] = C[2kk][n], Co[kk][n] = C[2kk+1][n], n<256.
__global__ __launch_bounds__(256) void fill_dct_half(unsigned short* __restrict__ Ce,
                                                     unsigned short* __restrict__ Co) {
    int idx = blockIdx.x * 256 + threadIdx.x;     // 0..131071
    int par = idx >> 16;
    int kk = (idx >> 8) & 255;
    int n = idx & 255;
    int k = 2 * kk + par;
    int m = ((2 * n + 1) * k) & 2047;
    float ang = (float)m * 3.0679615757712823e-3f;   // * pi/1024
    float s = (k == 0) ? 0.04419417382415922f : 0.0625f;
    unsigned short v = f2bf(s * cosf(ang));
    if (par) Co[kk * 256 + n] = v; else Ce[kk * 256 + n] = v;
}

#define GLB(p) ((const __attribute__((address_space(1))) unsigned int*)(const void*)(p))
#define LDS(p) ((__attribute__((address_space(3))) unsigned int*)(p))

// R11: persistent tile-looped blocks with a CROSS-TILE continuous pipeline.
//  - R10 clean A/B showed depth/occupancy are null -> floor is per-block
//    ramp/drain (naked prologue RTT, vmcnt(0) taper, epilogue drain,
//    dispatch gap) x 6 blocks/CU. Fix: grid 512 (2/CU, all resident),
//    each block loops over 3 tiles; stage/lr at kt>=5 target the NEXT
//    tile's steps 0..2, so the counted-vmcnt invariant (retire stage(g+1)
//    with vmcnt(18)/(10)) holds across the seam; taper only on last tile.
//  - pass-1 epilogue transpose moved to dedicated smE region (LDS 73KB,
//    still 2 blocks/CU) and __syncthreads replaced by lgkmcnt(0)+s_barrier
//    (syncthreads would emit vmcnt(0) and drain the live pipeline).
//  - epilogue global stores enter the vmcnt FIFO as OLDEST entries; the
//    steady vmcnt(18)/(10) waits retire them first (adds ~store-ack,
//    covered by one iteration) - counts stay correct.
// PASS 1: T'[k][r] = sum_{n<256} (x[r][n] +- x[r][511-n]) * Ce/Co[k'][n]
// PASS 2: Out[q][k] = sum_{r<256} Ce/Co[q'][r] * (T'[k][r] +- T'[k][511-r])
template <int PASS>
__global__ __launch_bounds__(256, 2) void gemm_dct(const void* __restrict__ Ap,
                                                   const unsigned short* __restrict__ Ce,
                                                   const unsigned short* __restrict__ Cop,
                                                   void* __restrict__ Outp,
                                                   size_t strideIn, size_t strideOut,
                                                   int tiles, int tpb) {
    const int nwg = (int)gridDim.x;
    const int cpx = nwg >> 3;
    const int bid = (int)blockIdx.x;
    const int swzb = (bid & 7) * cpx + (bid >> 3);  // bijective XCD swizzle (nwg%8==0)
    const int first = swzb * tpb;
    int nt = tiles - first;
    if (nt > tpb) nt = tpb;
    if (nt <= 0) return;

    // p1: 20480 staging (As reg 2x4096, Bs gload 3x4096) + 16896 epilogue = 37376
    // p2: 20480 staging (As gload 3x4096, Bs reg 2x4096)
    __shared__ unsigned short sm[PASS == 1 ? 37376 : 20480];
    unsigned short* const As = sm;
    unsigned short* const Bs = sm + (PASS == 1 ? 8192 : 12288);
    unsigned short* const Rs = (PASS == 1) ? As : Bs;   // reg-staged side (2 bufs)
    unsigned short* const Gs = (PASS == 1) ? Bs : As;   // gload side (3 bufs)
    unsigned short* const smE = sm + 20480;             // p1 epilogue transpose

    const int t = threadIdx.x;
    const int lane = t & 63;
    const int wave = t >> 6;
    const int wr = wave >> 1, wc = wave & 1;
    const int lr = lane & 15;
    const int kgx = ((lane >> 4) * 8) ^ (((lr >> 1) & 3) << 3);

    // global_load_lds staging (Ce/Co side), 128x32 tile, pre-swizzled source
    const int srow = t >> 2;
    const int sslot = t & 3;
    const int scol = (sslot ^ ((srow >> 1) & 3)) * 8;

    // reg staging: thread -> (row 0..127, 16-elem half of the 32-col step)
    const int frow = t >> 1;
    const int fhalf = t & 1;
    const int fs0 = fhalf * 2;
    const int fxw = (frow >> 1) & 3;
    const int fslot0 = (fs0 ^ fxw) * 8;
    const int fslot1 = ((fs0 + 1) ^ fxw) * 8;

    struct TileP {
        const float* Xf;
        const unsigned short* Tp;
        const unsigned short* G;
        float sgnf;
        int grow0, row0, col0, bx, by, bz;
    };
    auto mk = [&](int nid) {
        TileP P;
        P.bx = nid & 3; P.by = (nid >> 2) & 3; P.bz = nid >> 4;
        if constexpr (PASS == 1) {
            P.Xf = (const float*)Ap + (size_t)P.bz * strideIn; P.Tp = nullptr;
            P.row0 = P.by * 128; P.col0 = P.bx * 128;
            P.G = (P.bx < 2) ? Ce : Cop; P.grow0 = (P.bx & 1) * 128;
            P.sgnf = (P.bx >= 2) ? -1.0f : 1.0f;
        } else {
            P.Xf = nullptr; P.Tp = (const unsigned short*)Ap + (size_t)P.bz * strideIn;
            P.col0 = P.bx * 128; P.row0 = 0;
            P.G = (P.by < 2) ? Ce : Cop; P.grow0 = (P.by & 1) * 128;
            P.sgnf = (P.by >= 2) ? -1.0f : 1.0f;
        }
        return P;
    };

    f32x4 acc[4][4] = {};

    // depth-2 raw tiles (fwd + mirror), two named sets (static indexing only)
    f32x4 rf0[4], rm0[4], rf1[4], rm1[4];     // pass 1 (fp32)
    bf16x8 gf0[2], gm0[2], gf1[2], gm1[2];    // pass 2 (bf16)

    auto stageG = [&](const TileP& P, int bofs, int k0) {
        __builtin_amdgcn_global_load_lds(GLB(P.G + (size_t)(P.grow0 + srow) * 256 + k0 + scol),
                                         LDS(&Gs[bofs + srow * 32 + sslot * 8]), 16, 0, 0);
        __builtin_amdgcn_global_load_lds(GLB(P.G + (size_t)(P.grow0 + 64 + srow) * 256 + k0 + scol),
                                         LDS(&Gs[bofs + (64 + srow) * 32 + sslot * 8]), 16, 0, 0);
    };
    auto lr1 = [&](const TileP& P, f32x4 (&rf)[4], f32x4 (&rm)[4], int k0) {
        const float* bfp = P.Xf + (size_t)(P.row0 + frow) * NN + k0 + fhalf * 16;
        const float* bmp = P.Xf + (size_t)(P.row0 + frow) * NN + (496 - k0 - fhalf * 16);
#pragma unroll
        for (int q = 0; q < 4; ++q) {
            rf[q] = *reinterpret_cast<const f32x4*>(bfp + 4 * q);
            rm[q] = *reinterpret_cast<const f32x4*>(bmp + 4 * q);
        }
    };
    auto cw1 = [&](const TileP& P, f32x4 (&rf)[4], f32x4 (&rm)[4], int bofs) {
        unsigned p[8];
#pragma unroll
        for (int q = 0; q < 8; ++q) {
            const int j0 = 2 * q, j1 = 2 * q + 1;
            const int r0 = 15 - j0, r1 = 15 - j1;
            float s0 = fmaf(P.sgnf, rm[r0 >> 2][r0 & 3], rf[j0 >> 2][j0 & 3]);
            float s1 = fmaf(P.sgnf, rm[r1 >> 2][r1 & 3], rf[j1 >> 2][j1 & 3]);
            p[q] = cvtpk_bf16(s0, s1);
        }
        u32x4 w0 = {p[0], p[1], p[2], p[3]};
        u32x4 w1 = {p[4], p[5], p[6], p[7]};
        *reinterpret_cast<u32x4*>(&Rs[bofs + frow * 32 + fslot0]) = w0;
        *reinterpret_cast<u32x4*>(&Rs[bofs + frow * 32 + fslot1]) = w1;
    };
    auto lr2 = [&](const TileP& P, bf16x8 (&gf)[2], bf16x8 (&gm)[2], int k0) {
        const unsigned short* bfp = P.Tp + (size_t)(P.col0 + frow) * NN + k0 + fhalf * 16;
        const unsigned short* bmp = P.Tp + (size_t)(P.col0 + frow) * NN + (496 - k0 - fhalf * 16);
        gf[0] = *reinterpret_cast<const bf16x8*>(bfp);
        gf[1] = *reinterpret_cast<const bf16x8*>(bfp + 8);
        gm[0] = *reinterpret_cast<const bf16x8*>(bmp);
        gm[1] = *reinterpret_cast<const bf16x8*>(bmp + 8);
    };
    auto cw2 = [&](const TileP& P, bf16x8 (&gf)[2], bf16x8 (&gm)[2], int bofs) {
        unsigned p[8];
#pragma unroll
        for (int q = 0; q < 8; ++q) {
            const int j0 = 2 * q, j1 = 2 * q + 1;
            const int r0 = 15 - j0, r1 = 15 - j1;
            float a0 = bf2f((unsigned short)gf[j0 >> 3][j0 & 7]);
            float a1 = bf2f((unsigned short)gf[j1 >> 3][j1 & 7]);
            float b0 = bf2f((unsigned short)gm[r0 >> 3][r0 & 7]);
            float b1 = bf2f((unsigned short)gm[r1 >> 3][r1 & 7]);
            p[q] = cvtpk_bf16(fmaf(P.sgnf, b0, a0), fmaf(P.sgnf, b1, a1));
        }
        u32x4 w0 = {p[0], p[1], p[2], p[3]};
        u32x4 w1 = {p[4], p[5], p[6], p[7]};
        *reinterpret_cast<u32x4*>(&Rs[bofs + frow * 32 + fslot0]) = w0;
        *reinterpret_cast<u32x4*>(&Rs[bofs + frow * 32 + fslot1]) = w1;
    };
    auto compute = [&](int rofs, int gofs) {
        const int aofs = (PASS == 1) ? rofs : gofs;
        const int bofs = (PASS == 1) ? gofs : rofs;
        bf16x8 a[4], b[4];
#pragma unroll
        for (int mi = 0; mi < 4; ++mi)
            a[mi] = *reinterpret_cast<const bf16x8*>(
                &As[aofs + (wr * 64 + mi * 16 + lr) * 32 + kgx]);
#pragma unroll
        for (int ni = 0; ni < 4; ++ni)
            b[ni] = *reinterpret_cast<const bf16x8*>(
                &Bs[bofs + (wc * 64 + ni * 16 + lr) * 32 + kgx]);
        __builtin_amdgcn_s_setprio(1);
#pragma unroll
        for (int mi = 0; mi < 4; ++mi)
#pragma unroll
            for (int ni = 0; ni < 4; ++ni)
                acc[mi][ni] = __builtin_amdgcn_mfma_f32_16x16x32_bf16(a[mi], b[ni],
                                                                      acc[mi][ni], 0, 0, 0);
        __builtin_amdgcn_s_setprio(0);
    };
    auto doLR = [&](const TileP& P, int s, int k0) {
        if constexpr (PASS == 1) {
            if (s & 1) lr1(P, rf1, rm1, k0); else lr1(P, rf0, rm0, k0);
        } else {
            if (s & 1) lr2(P, gf1, gm1, k0); else lr2(P, gf0, gm0, k0);
        }
    };
    auto doCW = [&](const TileP& P, int s) {
        const int bofs = (s & 1) * 4096;
        if constexpr (PASS == 1) {
            if (s & 1) cw1(P, rf1, rm1, bofs); else cw1(P, rf0, rm0, bofs);
        } else {
            if (s & 1) cw2(P, gf1, gm1, bofs); else cw2(P, gf0, gm0, bofs);
        }
    };

    // gload-side buffer offsets: cX = LDS short-offset for global step s%3==X.
    // Rotation per tile (+8 steps == +2 mod 3): c0'<-c2, c1'<-c0, c2'<-c1.
    int c0 = 0, c1 = 4096, c2 = 8192;
    auto gof = [&](int s) { int m = s % 3; return m == 0 ? c0 : (m == 1 ? c1 : c2); };

    TileP P0 = mk(first);
    TileP P1 = (nt > 1) ? mk(first + 1) : P0;

    // ---- prologue (once per block): tile0 step0 staged+written; steps 1,2 in flight ----
    stageG(P0, c0, 0);
    doLR(P0, 0, 0);
    asm volatile("" ::: "memory");      // pin FIFO: step0 VMEM first
    doCW(P0, 0);                        // implicit drain: raw(0) + stage(0)
    stageG(P0, c1, 32);
    asm volatile("" ::: "memory");      // pin: stage(1) before raw(1)/(2)
    doLR(P0, 1, 32);
    doLR(P0, 2, 64);
    asm volatile("s_waitcnt lgkmcnt(0)" ::: "memory");
    if constexpr (PASS == 1) asm volatile("s_waitcnt vmcnt(18)" ::: "memory");
    else                     asm volatile("s_waitcnt vmcnt(10)" ::: "memory");
    __builtin_amdgcn_s_barrier();

    // ---- tile loop: continuous 8-step pipeline per tile ----
    for (int tt = 0; tt < nt; ++tt) {
        const bool last = (tt == nt - 1);
#pragma unroll
        for (int kt = 0; kt < 8; ++kt) {
            // fold+write step kt+1 (raw loaded 2 steps earlier)
            if (kt < 7)        doCW(P0, kt + 1);
            else if (!last)    doCW(P1, 0);
            // gload step kt+2 (crosses into next tile at kt>=6)
            if (kt < 6)        stageG(P0, gof(kt + 2), (kt + 2) * 32);
            else if (!last)    stageG(P1, gof(kt + 2), (kt - 6) * 32);
            asm volatile("" ::: "memory");  // pin: stage(kt+2) before raw(kt+3)
            // raw step kt+3 (crosses at kt>=5)
            if (kt < 5)        doLR(P0, kt + 3, (kt + 3) * 32);
            else if (!last)    doLR(P1, kt + 3, (kt - 5) * 32);
            compute((kt & 1) * 4096, gof(kt));
            asm volatile("s_waitcnt lgkmcnt(0)" ::: "memory");
            if (!last || kt <= 4) {
                // steady: retire stage(g+1); epilogue stores (older) retire first
                if constexpr (PASS == 1) asm volatile("s_waitcnt vmcnt(18)" ::: "memory");
                else                     asm volatile("s_waitcnt vmcnt(10)" ::: "memory");
            } else if (kt == 5) {
                if constexpr (PASS == 1) asm volatile("s_waitcnt vmcnt(10)" ::: "memory");
                else                     asm volatile("s_waitcnt vmcnt(6)" ::: "memory");
            } else if (kt == 6) {
                asm volatile("s_waitcnt vmcnt(0)" ::: "memory");
            }
            if (kt < 7) __builtin_amdgcn_s_barrier();
        }

        // ---- tile epilogue. C/D frag: row = (lane>>4)*4 + reg, col = lane&15 ----
        if constexpr (PASS == 1) {
            unsigned short* T = (unsigned short*)Outp + (size_t)P0.bz * strideOut;
#pragma unroll
            for (int mi = 0; mi < 4; ++mi)
#pragma unroll
                for (int ni = 0; ni < 4; ++ni) {
                    int gr = wr * 64 + mi * 16 + (lane >> 4) * 4;   // local r
                    int gc = wc * 64 + ni * 16 + lr;                // local k'
                    ushort4 v;
                    v.x = f2bf(acc[mi][ni][0]);
                    v.y = f2bf(acc[mi][ni][1]);
                    v.z = f2bf(acc[mi][ni][2]);
                    v.w = f2bf(acc[mi][ni][3]);
                    *reinterpret_cast<ushort4*>(&smE[gc * 132 + gr]) = v;
                }
            // tile-boundary barrier: lgkm-only (NOT __syncthreads: that would
            // emit vmcnt(0) and drain the cross-tile load pipeline)
            asm volatile("s_waitcnt lgkmcnt(0)" ::: "memory");
            __builtin_amdgcn_s_barrier();
#pragma unroll
            for (int it = 0; it < 8; ++it) {
                int gcr = wave * 32 + it * 4 + (lane >> 4);            // local k'
                int physRow = (P0.bx & 1) * 256 + 2 * gcr + (P0.bx >> 1); // natural k
                int cb = lr * 8;
                u32x4 d = *reinterpret_cast<const u32x4*>(&smE[gcr * 132 + cb]);
                *reinterpret_cast<u32x4*>(&T[(size_t)physRow * NN + P0.row0 + cb]) = d;
            }
        } else {
            __builtin_amdgcn_s_barrier();   // tile boundary (cw writes flushed at kt=7)
            float* O = (float*)Outp + (size_t)P0.bz * strideOut;
#pragma unroll
            for (int mi = 0; mi < 4; ++mi)
#pragma unroll
                for (int ni = 0; ni < 4; ++ni) {
                    int gc = P0.col0 + wc * 64 + ni * 16 + lr;      // natural k col
#pragma unroll
                    for (int rr = 0; rr < 4; ++rr) {
                        int grl = wr * 64 + mi * 16 + (lane >> 4) * 4 + rr; // local q'
                        int ih = (P0.by & 1) * 128 + grl;
                        int q = 2 * ih + (P0.by >> 1);              // natural q row
                        O[(size_t)q * NN + gc] = acc[mi][ni][rr];
                    }
                }
        }

        if (!last) {
#pragma unroll
            for (int mi = 0; mi < 4; ++mi)
#pragma unroll
                for (int ni = 0; ni < 4; ++ni) acc[mi][ni] = f32x4{0.f, 0.f, 0.f, 0.f};
            P0 = P1;
            if (tt + 2 < nt) P1 = mk(first + tt + 2);
            int tmpo = c2; c2 = c1; c1 = c0; c0 = tmpo;   // +8 steps == +2 mod 3
        }
    }
}

extern "C" void kernel_launch(void* const* d_in, const int* in_sizes, int n_in,
                              void* d_out, int out_size, void* d_ws, size_t ws_size,
                              hipStream_t stream) {
    const float* x = (const float*)d_in[0];
    float* out = (float*)d_out;

    const int imgs = in_sizes[0] / (NN * NN);            // 96
    const size_t imgElems = (size_t)NN * NN;             // 262144
    const size_t imgB16 = imgElems * 2;                  // 512 KB

    unsigned short* Ce = (unsigned short*)d_ws;          // 128 KB
    unsigned short* Co = Ce + 65536;                     // 128 KB
    unsigned short* Tb = Co + 65536;                     // T' buffers

    long long budget = (long long)ws_size - 262144;
    int maxchunk = (int)(budget / (long long)imgB16);
    if (maxchunk < 1) maxchunk = 1;
    if (maxchunk > imgs) maxchunk = imgs;

    hipLaunchKernelGGL(fill_dct_half, dim3(512), dim3(256), 0, stream, Ce, Co);

    for (int i0 = 0; i0 < imgs; i0 += maxchunk) {
        int c = imgs - i0 < maxchunk ? imgs - i0 : maxchunk;
        int tiles = 16 * c;
        int blocks = tiles < 512 ? tiles : 512;          // %8==0 either way
        int tpb = (tiles + blocks - 1) / blocks;
        hipLaunchKernelGGL((gemm_dct<1>), dim3(blocks), dim3(256), 0, stream,
                           x + (size_t)i0 * imgElems, Ce, Co, Tb, imgElems, imgElems,
                           tiles, tpb);
        hipLaunchKernelGGL((gemm_dct<2>), dim3(blocks), dim3(256), 0, stream,
                           Tb, Ce, Co, out + (size_t)i0 * imgElems, imgElems, imgElems,
                           tiles, tpb);
    }
}

// Round 5
// 74.772 us; speedup vs baseline: 1.5005x; 1.5005x over previous
//
#include <hip/hip_runtime.h>
#include <math.h>

#define NN 512

typedef __attribute__((ext_vector_type(8))) short bf16x8;
typedef __attribute__((ext_vector_type(4))) float f32x4;
typedef __attribute__((ext_vector_type(4))) unsigned int u32x4;

__device__ inline unsigned short f2bf(float f) {
    unsigned u = __builtin_bit_cast(unsigned, f);
    u += 0x7fffu + ((u >> 16) & 1u);   // round-to-nearest-even
    return (unsigned short)(u >> 16);
}
__device__ inline float bf2f(unsigned short h) {
    unsigned u = ((unsigned)h) << 16;
    return __builtin_bit_cast(float, u);
}
__device__ inline unsigned cvtpk_bf16(float lo, float hi) {
    unsigned r;
    asm("v_cvt_pk_bf16_f32 %0, %1, %2" : "=v"(r) : "v"(lo), "v"(hi));
    return r;
}

// Parity-split DCT matrices: Ce[kk][n] = C[2kk][n], Co[kk][n] = C[2kk+1][n], n<256.
__global__ __launch_bounds__(256) void fill_dct_half(unsigned short* __restrict__ Ce,
                                                     unsigned short* __restrict__ Co) {
    int idx = blockIdx.x * 256 + threadIdx.x;     // 0..131071
    int par = idx >> 16;
    int kk = (idx >> 8) & 255;
    int n = idx & 255;
    int k = 2 * kk + par;
    int m = ((2 * n + 1) * k) & 2047;
    float ang = (float)m * 3.0679615757712823e-3f;   // * pi/1024
    float s = (k == 0) ? 0.04419417382415922f : 0.0625f;
    unsigned short v = f2bf(s * cosf(ang));
    if (par) Co[kk * 256 + n] = v; else Ce[kk * 256 + n] = v;
}

#define GLB(p) ((const __attribute__((address_space(1))) unsigned int*)(const void*)(p))
#define LDS(p) ((__attribute__((address_space(3))) unsigned int*)(p))

// R12: 512-thread / 8-wave blocks, half per-thread footprint -> 16 waves/CU.
//  - R11 (persistent loop) regressed: runtime tile loop re-spilled (VGPR=128,
//    FETCH 3.4x) and broke L2/L3 X-reuse. Reverted to per-tile blocks.
//  - R7==R10 at 8 waves/CU showed depth & block-count null; wave count was
//    never tested. 8 waves per block over the same 128x128 tile: wave grid
//    2x4, per-wave 64x32 (acc 32 regs), raw depth-2 32 regs (p1) ->
//    demand ~104 (p1) / ~88 (p2) under __launch_bounds__(512,4) cap 128:
//    no spill possible, 2 blocks/CU = 16 waves, finer-grained DRAM demand.
//  - quarter-row staging: thread owns (row=t>>2, quarter=t&3); fold partner
//    of fwd elem j (0..7) is mirror elem 7-j (base 504-k0-8q).
//  - vmcnt ledger (1 stage + 4 lr instr/iter p1; 1+2 p2):
//    p1 prologue 8, steady 9, tail kt5=5 kt6=0; p2: 4, 5, 3, 0.
// PASS 1: T'[k][r] = sum_{n<256} (x[r][n] +- x[r][511-n]) * Ce/Co[k'][n]
//         bx<2 even k (+), bx>=2 odd k (-). B=Ce/Co gload_lds; A=X reg-staged.
// PASS 2: Out[q][k] = sum_{r<256} Ce/Co[q'][r] * (T'[k][r] +- T'[k][511-r])
//         by<2 even q (+), by>=2 odd q (-). A=Ce/Co gload_lds; B=T' reg-staged.
template <int PASS>
__global__ __launch_bounds__(512, 4) void gemm_dct(const void* __restrict__ Ap,
                                                   const unsigned short* __restrict__ Ce,
                                                   const unsigned short* __restrict__ Cop,
                                                   void* __restrict__ Outp,
                                                   size_t strideIn, size_t strideOut) {
    const int nwg = (int)gridDim.x;
    const int cpx = nwg >> 3;
    const int bid = (int)blockIdx.x;
    const int nid = (bid & 7) * cpx + (bid >> 3);   // bijective XCD swizzle (nwg%8==0)
    const int bx = nid & 3;
    const int by = (nid >> 2) & 3;
    const int bz = nid >> 4;

    // staging 40960 B: reg side 2 bufs (8192 shorts), gload side 3 bufs (12288).
    // p1 adds 16896-short epilogue transpose region (total 74752 B).
    __shared__ unsigned short sm[PASS == 1 ? 37376 : 20480];
    unsigned short* const As = sm;
    unsigned short* const Bs = sm + (PASS == 1 ? 8192 : 12288);
    unsigned short* const Rs = (PASS == 1) ? As : Bs;   // reg-staged side (2 bufs)
    unsigned short* const Gs = (PASS == 1) ? Bs : As;   // gload side (3 bufs)
    unsigned short* const smE = sm + 20480;             // p1 epilogue transpose

    const int t = threadIdx.x;
    const int lane = t & 63;
    const int wave = t >> 6;                 // 0..7
    const int wr = wave >> 2, wc = wave & 3; // wave grid 2x4 over 128x128
    const int lr = lane & 15;
    const int kgx = ((lane >> 4) * 8) ^ (((lr >> 1) & 3) << 3);

    // gload staging (Ce/Co side), 128x32 tile: t -> (row t>>2, slot t&3),
    // pre-swizzled source col. LDS dest = wave-uniform base + lane*16 (verified).
    const int srow = t >> 2;
    const int sslot = t & 3;
    const int scol = (sslot ^ ((srow >> 1) & 3)) * 8;

    // reg staging: t -> (row t>>2, quarter t&3) of the 32-col step
    const int frow = t >> 2;
    const int fq = t & 3;
    const int fslot = (fq ^ ((frow >> 1) & 3)) * 8;

    const float* Xf = nullptr;
    const unsigned short* Tp = nullptr;
    const unsigned short* Gmat;
    int grow0, sgn, row0, col0;
    if constexpr (PASS == 1) {
        Xf = (const float*)Ap + (size_t)bz * strideIn;
        row0 = by * 128;
        col0 = bx * 128;
        Gmat = (bx < 2) ? Ce : Cop; grow0 = (bx & 1) * 128; sgn = (bx >= 2);
    } else {
        Tp = (const unsigned short*)Ap + (size_t)bz * strideIn;
        col0 = bx * 128;
        row0 = 0;
        Gmat = (by < 2) ? Ce : Cop; grow0 = (by & 1) * 128; sgn = (by >= 2);
    }
    const float sgnf = sgn ? -1.0f : 1.0f;

    f32x4 acc[4][2] = {};

    // depth-2 raw tiles (fwd + mirror), two named sets (static indexing only)
    f32x4 rfA[2], rmA[2], rfB[2], rmB[2];     // pass 1 (fp32, 8 elems each side)
    bf16x8 gfA, gmA, gfB, gmB;                // pass 2 (bf16)

    auto stageG = [&](int buf, int k0) {
        __builtin_amdgcn_global_load_lds(GLB(Gmat + (size_t)(grow0 + srow) * 256 + k0 + scol),
                                         LDS(&Gs[buf * 4096 + srow * 32 + sslot * 8]), 16, 0, 0);
    };
    auto lr1 = [&](f32x4 (&rf)[2], f32x4 (&rm)[2], int k0) {
        const float* bfp = Xf + (size_t)(row0 + frow) * NN + k0 + fq * 8;
        const float* bmp = Xf + (size_t)(row0 + frow) * NN + (504 - k0 - fq * 8);
        rf[0] = *reinterpret_cast<const f32x4*>(bfp);
        rf[1] = *reinterpret_cast<const f32x4*>(bfp + 4);
        rm[0] = *reinterpret_cast<const f32x4*>(bmp);
        rm[1] = *reinterpret_cast<const f32x4*>(bmp + 4);
    };
    auto cw1 = [&](f32x4 (&rf)[2], f32x4 (&rm)[2], int buf) {
        unsigned p[4];
#pragma unroll
        for (int q = 0; q < 4; ++q) {
            const int j0 = 2 * q, j1 = 2 * q + 1;
            const int r0 = 7 - j0, r1 = 7 - j1;
            float s0 = fmaf(sgnf, rm[r0 >> 2][r0 & 3], rf[j0 >> 2][j0 & 3]);
            float s1 = fmaf(sgnf, rm[r1 >> 2][r1 & 3], rf[j1 >> 2][j1 & 3]);
            p[q] = cvtpk_bf16(s0, s1);
        }
        u32x4 w = {p[0], p[1], p[2], p[3]};
        *reinterpret_cast<u32x4*>(&Rs[buf * 4096 + frow * 32 + fslot]) = w;
    };
    auto lr2 = [&](bf16x8& gf, bf16x8& gm, int k0) {
        const unsigned short* bfp = Tp + (size_t)(col0 + frow) * NN + k0 + fq * 8;
        const unsigned short* bmp = Tp + (size_t)(col0 + frow) * NN + (504 - k0 - fq * 8);
        gf = *reinterpret_cast<const bf16x8*>(bfp);
        gm = *reinterpret_cast<const bf16x8*>(bmp);
    };
    auto cw2 = [&](bf16x8& gf, bf16x8& gm, int buf) {
        unsigned p[4];
#pragma unroll
        for (int q = 0; q < 4; ++q) {
            const int j0 = 2 * q, j1 = 2 * q + 1;
            float a0 = bf2f((unsigned short)gf[j0]);
            float a1 = bf2f((unsigned short)gf[j1]);
            float b0 = bf2f((unsigned short)gm[7 - j0]);
            float b1 = bf2f((unsigned short)gm[7 - j1]);
            p[q] = cvtpk_bf16(fmaf(sgnf, b0, a0), fmaf(sgnf, b1, a1));
        }
        u32x4 w = {p[0], p[1], p[2], p[3]};
        *reinterpret_cast<u32x4*>(&Rs[buf * 4096 + frow * 32 + fslot]) = w;
    };
    auto compute = [&](int kt) {
        const int rofs = (kt & 1) * 4096;
        const int gofs = (kt % 3) * 4096;
        const int aofs = (PASS == 1) ? rofs : gofs;
        const int bofs = (PASS == 1) ? gofs : rofs;
        bf16x8 a[4], b[2];
#pragma unroll
        for (int mi = 0; mi < 4; ++mi)
            a[mi] = *reinterpret_cast<const bf16x8*>(
                &As[aofs + (wr * 64 + mi * 16 + lr) * 32 + kgx]);
#pragma unroll
        for (int ni = 0; ni < 2; ++ni)
            b[ni] = *reinterpret_cast<const bf16x8*>(
                &Bs[bofs + (wc * 32 + ni * 16 + lr) * 32 + kgx]);
        __builtin_amdgcn_s_setprio(1);
#pragma unroll
        for (int mi = 0; mi < 4; ++mi)
#pragma unroll
            for (int ni = 0; ni < 2; ++ni)
                acc[mi][ni] = __builtin_amdgcn_mfma_f32_16x16x32_bf16(a[mi], b[ni],
                                                                      acc[mi][ni], 0, 0, 0);
        __builtin_amdgcn_s_setprio(0);
    };
    auto doLR = [&](int s, int k0) {
        if constexpr (PASS == 1) {
            if (s & 1) lr1(rfB, rmB, k0); else lr1(rfA, rmA, k0);
        } else {
            if (s & 1) lr2(gfB, gmB, k0); else lr2(gfA, gmA, k0);
        }
    };
    auto doCW = [&](int s) {
        const int buf = s & 1;
        if constexpr (PASS == 1) {
            if (s & 1) cw1(rfB, rmB, buf); else cw1(rfA, rmA, buf);
        } else {
            if (s & 1) cw2(gfB, gmB, buf); else cw2(gfA, gmA, buf);
        }
    };

    // ---- prologue: step0 staged+written; raw steps 1,2 in flight ----
    stageG(0, 0);
    doLR(0, 0);
    asm volatile("" ::: "memory");      // pin FIFO: step0 VMEM first
    doCW(0);                            // dep-drain: raw(0) (+stage(0), older)
    stageG(1, 32);
    asm volatile("" ::: "memory");      // pin: stage(1) before raw(1)/(2)
    doLR(1, 32);
    doLR(2, 64);
    asm volatile("s_waitcnt lgkmcnt(0)" ::: "memory");
    if constexpr (PASS == 1) asm volatile("s_waitcnt vmcnt(8)" ::: "memory");
    else                     asm volatile("s_waitcnt vmcnt(4)" ::: "memory");
    __builtin_amdgcn_s_barrier();

    // ---- 8 K-steps, fully unrolled; 1 barrier per step ----
#pragma unroll
    for (int kt = 0; kt < 8; ++kt) {
        if (kt + 1 <= 7) doCW(kt + 1);              // fold+write (raw from kt-2)
        if (kt + 2 <= 7) stageG((kt + 2) % 3, (kt + 2) * 32);
        asm volatile("" ::: "memory");              // pin: stage(kt+2) before raw(kt+3)
        if (kt + 3 <= 7) doLR(kt + 3, (kt + 3) * 32);
        compute(kt);
        asm volatile("s_waitcnt lgkmcnt(0)" ::: "memory");
        if (kt <= 4) {
            // outstanding: stage(kt+1) lr(kt+2) stage(kt+2) lr(kt+3) -> retire stage(kt+1)
            if constexpr (PASS == 1) asm volatile("s_waitcnt vmcnt(9)" ::: "memory");
            else                     asm volatile("s_waitcnt vmcnt(5)" ::: "memory");
        } else if (kt == 5) {
            if constexpr (PASS == 1) asm volatile("s_waitcnt vmcnt(5)" ::: "memory");
            else                     asm volatile("s_waitcnt vmcnt(3)" ::: "memory");
        } else if (kt == 6) {
            asm volatile("s_waitcnt vmcnt(0)" ::: "memory");
        }
        if (kt < 7) __builtin_amdgcn_s_barrier();
    }

    // ---- epilogue. C/D frag: row = (lane>>4)*4 + reg, col = lane&15 ----
    if constexpr (PASS == 1) {
        // LDS-staged transposed store with parity row permutation (smE region:
        // no aliasing with staging -> no leading barrier needed).
        unsigned short* T = (unsigned short*)Outp + (size_t)bz * strideOut;
#pragma unroll
        for (int mi = 0; mi < 4; ++mi)
#pragma unroll
            for (int ni = 0; ni < 2; ++ni) {
                int gr = wr * 64 + mi * 16 + (lane >> 4) * 4;   // local r
                int gc = wc * 32 + ni * 16 + lr;                // local k'
                ushort4 v;
                v.x = f2bf(acc[mi][ni][0]);
                v.y = f2bf(acc[mi][ni][1]);
                v.z = f2bf(acc[mi][ni][2]);
                v.w = f2bf(acc[mi][ni][3]);
                *reinterpret_cast<ushort4*>(&smE[gc * 132 + gr]) = v;
            }
        asm volatile("s_waitcnt lgkmcnt(0)" ::: "memory");
        __builtin_amdgcn_s_barrier();
#pragma unroll
        for (int it = 0; it < 4; ++it) {
            int gcr = wave * 16 + it * 4 + (lane >> 4);         // local k'
            int physRow = (bx & 1) * 256 + 2 * gcr + (bx >> 1); // natural k
            int cb = lr * 8;
            u32x4 d = *reinterpret_cast<const u32x4*>(&smE[gcr * 132 + cb]);
            *reinterpret_cast<u32x4*>(&T[(size_t)physRow * NN + row0 + cb]) = d;
        }
    } else {
        float* O = (float*)Outp + (size_t)bz * strideOut;
#pragma unroll
        for (int mi = 0; mi < 4; ++mi)
#pragma unroll
            for (int ni = 0; ni < 2; ++ni) {
                int gc = col0 + wc * 32 + ni * 16 + lr;         // natural k col
#pragma unroll
                for (int rr = 0; rr < 4; ++rr) {
                    int grl = wr * 64 + mi * 16 + (lane >> 4) * 4 + rr;  // local q'
                    int ih = (by & 1) * 128 + grl;
                    int q = 2 * ih + (by >> 1);                 // natural q row
                    O[(size_t)q * NN + gc] = acc[mi][ni][rr];
                }
            }
    }
}

extern "C" void kernel_launch(void* const* d_in, const int* in_sizes, int n_in,
                              void* d_out, int out_size, void* d_ws, size_t ws_size,
                              hipStream_t stream) {
    const float* x = (const float*)d_in[0];
    float* out = (float*)d_out;

    const int imgs = in_sizes[0] / (NN * NN);            // 96
    const size_t imgElems = (size_t)NN * NN;             // 262144
    const size_t imgB16 = imgElems * 2;                  // 512 KB

    unsigned short* Ce = (unsigned short*)d_ws;          // 128 KB
    unsigned short* Co = Ce + 65536;                     // 128 KB
    unsigned short* Tb = Co + 65536;                     // T' buffers

    long long budget = (long long)ws_size - 262144;
    int maxchunk = (int)(budget / (long long)imgB16);
    if (maxchunk < 1) maxchunk = 1;
    if (maxchunk > imgs) maxchunk = imgs;

    hipLaunchKernelGGL(fill_dct_half, dim3(512), dim3(256), 0, stream, Ce, Co);

    for (int i0 = 0; i0 < imgs; i0 += maxchunk) {
        int c = imgs - i0 < maxchunk ? imgs - i0 : maxchunk;
        hipLaunchKernelGGL((gemm_dct<1>), dim3(16 * c), dim3(512), 0, stream,
                           x + (size_t)i0 * imgElems, Ce, Co, Tb, imgElems, imgElems);
        hipLaunchKernelGGL((gemm_dct<2>), dim3(16 * c), dim3(512), 0, stream,
                           Tb, Ce, Co, out + (size_t)i0 * imgElems, imgElems, imgElems);
    }
}